// Round 5
// baseline (432.864 us; speedup 1.0000x reference)
//
#include <hip/hip_runtime.h>
#include <hip/hip_fp16.h>
#include <math.h>

#define TID threadIdx.x

static constexpr int NN = 20000;
static constexpr int NE = 640000;
static constexpr int NT = 1000000;
static constexpr int C = 128;
static constexpr int E = 64;
static constexpr int LUTN = 4104;     // 4097 live rows + zero padding
static constexpr float CUT = 5.0f;
static constexpr float LN2 = 0.69314718055994530942f;

__device__ __forceinline__ float ssp(float x) {
    return fmaxf(x, 0.0f) + __logf(1.0f + __expf(-fabsf(x))) - LN2;
}

__device__ __forceinline__ ushort f2bf(float x) {
    uint u = __float_as_uint(x);
    return (ushort)((u + 0x7FFFu + ((u >> 16) & 1u)) >> 16);
}

__device__ __forceinline__ float bf2f(ushort u) {
    return __uint_as_float((uint)u << 16);
}

__global__ __launch_bounds__(256) void k_zero(float* __restrict__ p, int n) {
    int i = blockIdx.x * 256 + TID;
    if (i < n) p[i] = 0.0f;
}

// out[r][c] = sum_k A[r][k]*W[k][c], f32 out. A: nrows x 128, W: 128x128
__global__ __launch_bounds__(256) void k_gemm128(const float* __restrict__ A,
                                                 const float* __restrict__ W,
                                                 float* __restrict__ out, int nrows) {
    __shared__ float wL[C * C];
    __shared__ float aL[8][C];
    for (int i = TID; i < C * C; i += 256) wL[i] = W[i];
    const int rg = TID >> 5;
    const int c4 = (TID & 31) << 2;
    for (int base = blockIdx.x * 8; base < nrows; base += gridDim.x * 8) {
        __syncthreads();
        for (int i = TID; i < 8 * C; i += 256) {
            int r = base + (i >> 7);
            aL[i >> 7][i & 127] = (r < nrows) ? A[(size_t)r * C + (i & 127)] : 0.0f;
        }
        __syncthreads();
        float4 acc = {0.f, 0.f, 0.f, 0.f};
        #pragma unroll 16
        for (int k = 0; k < C; ++k) {
            float a = aL[rg][k];
            const float4 w4 = *(const float4*)&wL[k * C + c4];
            acc.x = fmaf(a, w4.x, acc.x);
            acc.y = fmaf(a, w4.y, acc.y);
            acc.z = fmaf(a, w4.z, acc.z);
            acc.w = fmaf(a, w4.w, acc.w);
        }
        int r = base + rg;
        if (r < nrows) *(float4*)&out[(size_t)r * C + c4] = acc;
    }
}

// Same GEMM but bf16 output (for h)
__global__ __launch_bounds__(256) void k_gemm128b(const float* __restrict__ A,
                                                  const float* __restrict__ W,
                                                  ushort* __restrict__ outB, int nrows) {
    __shared__ float wL[C * C];
    __shared__ float aL[8][C];
    for (int i = TID; i < C * C; i += 256) wL[i] = W[i];
    const int rg = TID >> 5;
    const int c4 = (TID & 31) << 2;
    for (int base = blockIdx.x * 8; base < nrows; base += gridDim.x * 8) {
        __syncthreads();
        for (int i = TID; i < 8 * C; i += 256) {
            int r = base + (i >> 7);
            aL[i >> 7][i & 127] = (r < nrows) ? A[(size_t)r * C + (i & 127)] : 0.0f;
        }
        __syncthreads();
        float4 acc = {0.f, 0.f, 0.f, 0.f};
        #pragma unroll 16
        for (int k = 0; k < C; ++k) {
            float a = aL[rg][k];
            const float4 w4 = *(const float4*)&wL[k * C + c4];
            acc.x = fmaf(a, w4.x, acc.x);
            acc.y = fmaf(a, w4.y, acc.y);
            acc.z = fmaf(a, w4.z, acc.z);
            acc.w = fmaf(a, w4.w, acc.w);
        }
        int r = base + rg;
        if (r < nrows) {
            ushort4 u = {f2bf(acc.x), f2bf(acc.y), f2bf(acc.z), f2bf(acc.w)};
            *(ushort4*)&outB[(size_t)r * C + c4] = u;
        }
    }
}

// Build lutB[i][c] = bf16( (ssp(rb(i*delta)@W2b1)@W2b2)[c] ); rows with d>=CUT are ~0.
__global__ __launch_bounds__(256) void k_lut(const float* __restrict__ W2b1,
                                             const float* __restrict__ W2b2,
                                             ushort* __restrict__ lutB) {
    __shared__ float w1[E * E];
    __shared__ float w2[E * C];
    __shared__ float rbL[8][E];
    __shared__ float hid[8][E];
    for (int i = TID; i < E * E; i += 256) w1[i] = W2b1[i];
    for (int i = TID; i < E * C; i += 256) w2[i] = W2b2[i];
    const int jj = TID & 63;
    const int esA = TID >> 6;
    const int eg = TID >> 5;
    const int c4 = (TID & 31) << 2;
    const float gamma = 81.92f;
    const float cstep = CUT / 63.0f;
    const float delta = CUT / 4096.0f;
    const int base = blockIdx.x * 8;
    __syncthreads();
    #pragma unroll
    for (int s = 0; s < 2; ++s) {
        int es = esA + 4 * s;
        float d = (float)(base + es) * delta;
        float cv = (d < CUT) ? 0.5f * (1.0f + __cosf((float)M_PI * d / CUT)) : 0.0f;
        float dd = d - (float)jj * cstep;
        rbL[es][jj] = __expf(-gamma * dd * dd) * cv;
    }
    __syncthreads();
    #pragma unroll
    for (int s = 0; s < 2; ++s) {
        int es = esA + 4 * s;
        float a = 0.f;
        #pragma unroll 16
        for (int k = 0; k < E; ++k)
            a = fmaf(rbL[es][k], w1[k * E + jj], a);
        hid[es][jj] = ssp(a);
    }
    __syncthreads();
    float4 o = {0.f, 0.f, 0.f, 0.f};
    #pragma unroll
    for (int j = 0; j < E; ++j) {
        float t = hid[eg][j];
        const float4 w4 = *(const float4*)&w2[j * C + c4];
        o.x = fmaf(t, w4.x, o.x);
        o.y = fmaf(t, w4.y, o.y);
        o.z = fmaf(t, w4.z, o.z);
        o.w = fmaf(t, w4.w, o.w);
    }
    int row = base + eg;
    if (row < LUTN) {
        ushort4 u = {f2bf(o.x), f2bf(o.y), f2bf(o.z), f2bf(o.w)};
        *(ushort4*)&lutB[(size_t)row * C + c4] = u;
    }
}

__global__ __launch_bounds__(256) void k_hist(const int* __restrict__ nl0,
                                              const int* __restrict__ tidx,
                                              int* __restrict__ histE,
                                              int* __restrict__ histT) {
    for (int i = blockIdx.x * 256 + TID; i < NT; i += gridDim.x * 256) {
        if (i < NE) atomicAdd(&histE[nl0[i]], 1);
        atomicAdd(&histT[tidx[3 * i + 1]], 1);
    }
}

__device__ void scan_one(const int* __restrict__ hist, int* __restrict__ start,
                         int* __restrict__ cur, int n) {
    __shared__ int wsum[16];
    __shared__ int carryS;
    const int lane = TID & 63;
    const int wv = TID >> 6;
    if (TID == 0) carryS = 0;
    __syncthreads();
    for (int base = 0; base < n; base += 1024) {
        int i = base + TID;
        int v = (i < n) ? hist[i] : 0;
        int acc = v;
        #pragma unroll
        for (int off = 1; off < 64; off <<= 1) {
            int t = __shfl_up(acc, off, 64);
            if (lane >= off) acc += t;
        }
        if (lane == 63) wsum[wv] = acc;
        __syncthreads();
        int woff = 0;
        for (int w = 0; w < wv; ++w) woff += wsum[w];
        int carry = carryS;
        int excl = carry + woff + acc - v;
        if (i < n) { start[i] = excl; cur[i] = excl; }
        __syncthreads();
        if (TID == 1023) carryS = excl + v;
        __syncthreads();
    }
}

__global__ __launch_bounds__(1024) void k_scan2(const int* __restrict__ hE, int* __restrict__ sE,
                                                int* __restrict__ cE,
                                                const int* __restrict__ hT, int* __restrict__ sT,
                                                int* __restrict__ cT) {
    if (blockIdx.x == 0) scan_one(hE, sE, cE, NN);
    else                 scan_one(hT, sT, cT, NN);
}

// Counting-sort scatter with PACKED payloads (one wide store per item).
__global__ __launch_bounds__(256) void k_scatter(const int* __restrict__ nl0,
                                                 const int* __restrict__ nl1,
                                                 const float* __restrict__ dist,
                                                 const int* __restrict__ tidx,
                                                 const float* __restrict__ angles,
                                                 const float* __restrict__ rij,
                                                 const float* __restrict__ rik,
                                                 int* __restrict__ curE, int* __restrict__ curT,
                                                 int4* __restrict__ eS,
                                                 int2* __restrict__ tS) {
    for (int i = blockIdx.x * 256 + TID; i < NT; i += gridDim.x * 256) {
        if (i < NE) {
            int n0 = nl0[i];
            int pos = atomicAdd(&curE[n0], 1);
            // fixed-point LUT coordinate: idx = tq>>8, frac = (tq&255)/256
            uint tq = (uint)fmaf(dist[i], 209715.2f, 0.5f);   // d * (4096/5) * 256
            eS[pos] = make_int4((int)tq, n0, nl1[i], 0);
        }
        int t1 = tidx[3 * i + 1];
        int pos = atomicAdd(&curT[t1], 1);
        uint ab = ((uint)__half_as_ushort(__float2half_rn(rik[i])) << 16)
                | (uint)__half_as_ushort(__float2half_rn(rij[i]));
        uint cc = (uint)__half_as_ushort(__float2half_rn(__cosf(angles[i])));
        tS[pos] = make_int2((int)ab, (int)cc);
    }
}

// Fused: per edge-slot r, usum = sum_t ssp(tbf@W3b1); w3 = usum@W3b2 (in-wave matvec);
// agg[nl0[r]] += h[r]*w3. One wave per r.
__global__ __launch_bounds__(256) void k_trip_node(const int* __restrict__ startT,
                                                   const int* __restrict__ histT,
                                                   const int2* __restrict__ tS,
                                                   const float* __restrict__ W3b1,
                                                   const float* __restrict__ W3b2,
                                                   const ushort* __restrict__ hB,
                                                   const int* __restrict__ nl0,
                                                   float* __restrict__ agg) {
    __shared__ float w2[64 * C];   // 32 KB
    for (int i = TID; i < 64 * C; i += 256) w2[i] = W3b2[i];
    __syncthreads();
    const int lane = TID & 63;
    const int wv = TID >> 6;
    const float w1a = W3b1[lane];
    const float w1b = W3b1[64 + lane];
    const float w1c = W3b1[128 + lane];
    for (int r = blockIdx.x * 4 + wv; r < NN; r += gridDim.x * 4) {
        const int s0 = startT[r];
        const int cnt = histT[r];
        float usum = 0.f;
        for (int base = 0; base < cnt; base += 64) {
            const int n = min(64, cnt - base);
            float ri = 0.f, rk = 0.f, ca = 0.f;
            if (lane < n) {
                int2 p = tS[s0 + base + lane];
                ri = __half2float(__ushort_as_half((ushort)(p.x & 0xFFFF)));
                rk = __half2float(__ushort_as_half((ushort)((uint)p.x >> 16)));
                ca = __half2float(__ushort_as_half((ushort)(p.y & 0xFFFF)));
            }
            for (int i = 0; i < n; ++i) {
                float riB = __shfl(ri, i, 64);
                float rkB = __shfl(rk, i, 64);
                float caB = __shfl(ca, i, 64);
                float x = fmaf(riB, w1a, fmaf(rkB, w1b, caB * w1c));
                usum += ssp(x);
            }
        }
        // w3 = usum-vec @ W3b2; this lane produces cols lane and lane+64
        float o0 = 0.f, o1 = 0.f;
        #pragma unroll 8
        for (int k = 0; k < 64; ++k) {
            float uk = __shfl(usum, k, 64);
            o0 = fmaf(uk, w2[k * C + lane], o0);
            o1 = fmaf(uk, w2[k * C + 64 + lane], o1);
        }
        const int n0 = nl0[r];
        float h0 = bf2f(hB[(size_t)r * C + lane]);
        float h1 = bf2f(hB[(size_t)r * C + 64 + lane]);
        unsafeAtomicAdd(&agg[(size_t)n0 * C + lane], o0 * h0);
        unsafeAtomicAdd(&agg[(size_t)n0 * C + 64 + lane], o1 * h1);
    }
}

// Hot kernel: per sorted edge, out = lerp(lutB, tq) * hB[n1]; run-segmented sum -> agg[n0]
__global__ __launch_bounds__(256) void k_edges_lut(const int4* __restrict__ eS,
                                                   const ushort* __restrict__ hB,
                                                   const ushort* __restrict__ lutB,
                                                   float* __restrict__ agg) {
    __shared__ uint tqsh[256];
    __shared__ int n0sh[256];
    __shared__ int n1sh[256];
    const int c4 = (TID & 31) << 2;
    const int g = TID >> 5;                 // 8 groups x 32 edges
    const int nchunk = NE / 256;
    for (int ch = blockIdx.x; ch < nchunk; ch += gridDim.x) {
        __syncthreads();
        {
            int4 p = eS[ch * 256 + TID];
            tqsh[TID] = (uint)p.x;
            n0sh[TID] = p.y;
            n1sh[TID] = p.z;
        }
        __syncthreads();
        float4 acc = {0.f, 0.f, 0.f, 0.f};
        int cur = n0sh[g * 32];
        #pragma unroll 4
        for (int j = 0; j < 32; ++j) {
            int e = g * 32 + j;
            uint tq = tqsh[e];
            int idx = min((int)(tq >> 8), LUTN - 2);
            float fr = (float)(tq & 255u) * (1.0f / 256.0f);
            const ushort4 A4 = *(const ushort4*)&lutB[(size_t)idx * C + c4];
            const ushort4 B4 = *(const ushort4*)&lutB[(size_t)(idx + 1) * C + c4];
            const ushort4 hb = *(const ushort4*)&hB[(size_t)n1sh[e] * C + c4];
            float ax = bf2f(A4.x), ay = bf2f(A4.y), az = bf2f(A4.z), aw = bf2f(A4.w);
            float ox = fmaf(fr, bf2f(B4.x) - ax, ax);
            float oy = fmaf(fr, bf2f(B4.y) - ay, ay);
            float oz = fmaf(fr, bf2f(B4.z) - az, az);
            float ow = fmaf(fr, bf2f(B4.w) - aw, aw);
            acc.x = fmaf(ox, bf2f(hb.x), acc.x);
            acc.y = fmaf(oy, bf2f(hb.y), acc.y);
            acc.z = fmaf(oz, bf2f(hb.z), acc.z);
            acc.w = fmaf(ow, bf2f(hb.w), acc.w);
            int nxt = (j < 31) ? n0sh[e + 1] : -1;
            if (nxt != cur) {
                float* dst = &agg[(size_t)cur * C + c4];
                unsafeAtomicAdd(dst + 0, acc.x);
                unsafeAtomicAdd(dst + 1, acc.y);
                unsafeAtomicAdd(dst + 2, acc.z);
                unsafeAtomicAdd(dst + 3, acc.w);
                acc = (float4){0.f, 0.f, 0.f, 0.f};
                cur = nxt;
            }
        }
    }
}

extern "C" void kernel_launch(void* const* d_in, const int* in_sizes, int n_in,
                              void* d_out, int out_size, void* d_ws, size_t ws_size,
                              hipStream_t stream) {
    const float* features = (const float*)d_in[0];
    const float* ndist    = (const float*)d_in[1];
    const int*   nlist    = (const int*)d_in[2];
    const int*   tidx     = (const int*)d_in[3];
    const float* angles   = (const float*)d_in[4];
    const float* rij      = (const float*)d_in[5];
    const float* rik      = (const float*)d_in[6];
    const float* W_pre    = (const float*)d_in[7];
    const float* W2b1     = (const float*)d_in[8];
    const float* W2b2     = (const float*)d_in[9];
    const float* W3b1     = (const float*)d_in[10];
    const float* W3b2     = (const float*)d_in[11];
    const float* W_post   = (const float*)d_in[12];
    float* out = (float*)d_out;

    char* w = (char*)d_ws;
    float* agg   = (float*)w;   w += (size_t)NN * C * 4;    // 10.24 MB
    int* histE   = (int*)w;     w += (size_t)NN * 4;
    int* histT   = (int*)w;     w += (size_t)NN * 4;
    ushort* hB   = (ushort*)w;  w += (size_t)NN * C * 2;    // 5.12 MB
    ushort* lutB = (ushort*)w;  w += (size_t)LUTN * C * 2;  // 1.05 MB
    int4* eS     = (int4*)w;    w += (size_t)NE * 16;       // 10.24 MB
    int2* tS     = (int2*)w;    w += (size_t)NT * 8;        // 8 MB
    int* startE  = (int*)w;     w += (size_t)NN * 4;
    int* startT  = (int*)w;     w += (size_t)NN * 4;
    int* curE    = (int*)w;     w += (size_t)NN * 4;
    int* curT    = (int*)w;     w += (size_t)NN * 4;

    const int* nl0 = nlist;
    const int* nl1 = nlist + NE;

    // zero agg + histE + histT (contiguous)
    hipLaunchKernelGGL(k_zero, dim3((NN * C + 2 * NN + 255) / 256), dim3(256), 0, stream,
                       agg, NN * C + 2 * NN);
    hipLaunchKernelGGL(k_gemm128b, dim3(320), dim3(256), 0, stream,
                       features, W_pre, hB, NN);
    hipLaunchKernelGGL(k_lut, dim3((LUTN + 7) / 8), dim3(256), 0, stream,
                       W2b1, W2b2, lutB);
    hipLaunchKernelGGL(k_hist, dim3(2048), dim3(256), 0, stream,
                       nl0, tidx, histE, histT);
    hipLaunchKernelGGL(k_scan2, dim3(2), dim3(1024), 0, stream,
                       histE, startE, curE, histT, startT, curT);
    hipLaunchKernelGGL(k_scatter, dim3(2048), dim3(256), 0, stream,
                       nl0, nl1, ndist, tidx, angles, rij, rik,
                       curE, curT, eS, tS);
    hipLaunchKernelGGL(k_trip_node, dim3(1250), dim3(256), 0, stream,
                       startT, histT, tS, W3b1, W3b2, hB, nl0, agg);
    hipLaunchKernelGGL(k_edges_lut, dim3(2500), dim3(256), 0, stream,
                       eS, hB, lutB, agg);
    hipLaunchKernelGGL(k_gemm128, dim3(320), dim3(256), 0, stream,
                       agg, W_post, out, NN);
}

// Round 6
// 356.282 us; speedup vs baseline: 1.2149x; 1.2149x over previous
//
#include <hip/hip_runtime.h>
#include <hip/hip_fp16.h>
#include <math.h>

#define TID threadIdx.x

typedef ushort u16x8 __attribute__((ext_vector_type(8)));

static constexpr int NN = 20000;
static constexpr int NE = 640000;
static constexpr int NT = 1000000;
static constexpr int C = 128;
static constexpr int E = 64;
static constexpr int LUTN = 4104;     // 4097 live rows + zero padding
static constexpr float CUT = 5.0f;
static constexpr float LN2 = 0.69314718055994530942f;

__device__ __forceinline__ float ssp(float x) {
    return fmaxf(x, 0.0f) + __logf(1.0f + __expf(-fabsf(x))) - LN2;
}

__device__ __forceinline__ ushort f2bf(float x) {
    uint u = __float_as_uint(x);
    return (ushort)((u + 0x7FFFu + ((u >> 16) & 1u)) >> 16);
}

__device__ __forceinline__ float bf2f(ushort u) {
    return __uint_as_float((uint)u << 16);
}

__global__ __launch_bounds__(256) void k_zero(float* __restrict__ p, int n) {
    int i = blockIdx.x * 256 + TID;
    if (i < n) p[i] = 0.0f;
}

// ---- 128x128 GEMM, bf16 weights in LDS, 16 rows per block, no row loop ----
// out f32 variant
__global__ __launch_bounds__(256) void k_gemm16f(const float* __restrict__ A,
                                                 const float* __restrict__ W,
                                                 float* __restrict__ out, int nrows) {
    __shared__ ushort wB[C * C];       // 32 KB bf16
    __shared__ float aL[16][132];      // 8.25 KB, padded: 16B-aligned rows, bank-spread
    for (int i = TID; i < C * C / 4; i += 256) {
        float4 w4 = ((const float4*)W)[i];
        ushort4 u = {f2bf(w4.x), f2bf(w4.y), f2bf(w4.z), f2bf(w4.w)};
        ((ushort4*)wB)[i] = u;
    }
    const int base = blockIdx.x * 16;
    for (int i = TID; i < 512; i += 256) {
        int r = base + (i >> 5);
        float4 v = (r < nrows) ? ((const float4*)A)[(size_t)r * 32 + (i & 31)]
                               : (float4){0.f, 0.f, 0.f, 0.f};
        *(float4*)&aL[i >> 5][(i & 31) << 2] = v;
    }
    __syncthreads();
    const int rg = TID >> 4;          // 0..15 row in chunk
    const int c8 = (TID & 15) << 3;   // 8 cols per thread
    float acc[8] = {0.f, 0.f, 0.f, 0.f, 0.f, 0.f, 0.f, 0.f};
    #pragma unroll 8
    for (int k = 0; k < C; ++k) {
        float a = aL[rg][k];
        u16x8 wv = *(const u16x8*)&wB[k * C + c8];
        #pragma unroll
        for (int j = 0; j < 8; ++j) acc[j] = fmaf(a, bf2f(wv[j]), acc[j]);
    }
    int r = base + rg;
    if (r < nrows) {
        float4 o0 = {acc[0], acc[1], acc[2], acc[3]};
        float4 o1 = {acc[4], acc[5], acc[6], acc[7]};
        *(float4*)&out[(size_t)r * C + c8] = o0;
        *(float4*)&out[(size_t)r * C + c8 + 4] = o1;
    }
}

// out bf16 variant (for h)
__global__ __launch_bounds__(256) void k_gemm16b(const float* __restrict__ A,
                                                 const float* __restrict__ W,
                                                 ushort* __restrict__ outB, int nrows) {
    __shared__ ushort wB[C * C];
    __shared__ float aL[16][132];
    for (int i = TID; i < C * C / 4; i += 256) {
        float4 w4 = ((const float4*)W)[i];
        ushort4 u = {f2bf(w4.x), f2bf(w4.y), f2bf(w4.z), f2bf(w4.w)};
        ((ushort4*)wB)[i] = u;
    }
    const int base = blockIdx.x * 16;
    for (int i = TID; i < 512; i += 256) {
        int r = base + (i >> 5);
        float4 v = (r < nrows) ? ((const float4*)A)[(size_t)r * 32 + (i & 31)]
                               : (float4){0.f, 0.f, 0.f, 0.f};
        *(float4*)&aL[i >> 5][(i & 31) << 2] = v;
    }
    __syncthreads();
    const int rg = TID >> 4;
    const int c8 = (TID & 15) << 3;
    float acc[8] = {0.f, 0.f, 0.f, 0.f, 0.f, 0.f, 0.f, 0.f};
    #pragma unroll 8
    for (int k = 0; k < C; ++k) {
        float a = aL[rg][k];
        u16x8 wv = *(const u16x8*)&wB[k * C + c8];
        #pragma unroll
        for (int j = 0; j < 8; ++j) acc[j] = fmaf(a, bf2f(wv[j]), acc[j]);
    }
    int r = base + rg;
    if (r < nrows) {
        u16x8 u;
        #pragma unroll
        for (int j = 0; j < 8; ++j) u[j] = f2bf(acc[j]);
        *(u16x8*)&outB[(size_t)r * C + c8] = u;
    }
}

// Build lutB[i][c] = bf16( (ssp(rb(i*delta)@W2b1)@W2b2)[c] ); rows with d>=CUT are 0.
__global__ __launch_bounds__(256) void k_lut(const float* __restrict__ W2b1,
                                             const float* __restrict__ W2b2,
                                             ushort* __restrict__ lutB) {
    __shared__ float w1[E * E];
    __shared__ float w2[E * C];
    __shared__ float rbL[8][E];
    __shared__ float hid[8][E];
    for (int i = TID; i < E * E; i += 256) w1[i] = W2b1[i];
    for (int i = TID; i < E * C; i += 256) w2[i] = W2b2[i];
    const int jj = TID & 63;
    const int esA = TID >> 6;
    const int eg = TID >> 5;
    const int c4 = (TID & 31) << 2;
    const float gamma = 81.92f;
    const float cstep = CUT / 63.0f;
    const float delta = CUT / 4096.0f;
    const int base = blockIdx.x * 8;
    __syncthreads();
    #pragma unroll
    for (int s = 0; s < 2; ++s) {
        int es = esA + 4 * s;
        float d = (float)(base + es) * delta;
        float cv = (d < CUT) ? 0.5f * (1.0f + __cosf((float)M_PI * d / CUT)) : 0.0f;
        float dd = d - (float)jj * cstep;
        rbL[es][jj] = __expf(-gamma * dd * dd) * cv;
    }
    __syncthreads();
    #pragma unroll
    for (int s = 0; s < 2; ++s) {
        int es = esA + 4 * s;
        float a = 0.f;
        #pragma unroll 16
        for (int k = 0; k < E; ++k)
            a = fmaf(rbL[es][k], w1[k * E + jj], a);
        hid[es][jj] = ssp(a);
    }
    __syncthreads();
    float4 o = {0.f, 0.f, 0.f, 0.f};
    #pragma unroll
    for (int j = 0; j < E; ++j) {
        float t = hid[eg][j];
        const float4 w4 = *(const float4*)&w2[j * C + c4];
        o.x = fmaf(t, w4.x, o.x);
        o.y = fmaf(t, w4.y, o.y);
        o.z = fmaf(t, w4.z, o.z);
        o.w = fmaf(t, w4.w, o.w);
    }
    int row = base + eg;
    if (row < LUTN) {
        ushort4 u = {f2bf(o.x), f2bf(o.y), f2bf(o.z), f2bf(o.w)};
        *(ushort4*)&lutB[(size_t)row * C + c4] = u;
    }
}

// Histogram pass ALSO records each item's arrival rank (enables atomic-free scatter).
__global__ __launch_bounds__(256) void k_hist(const int* __restrict__ nl0,
                                              const int* __restrict__ tidx,
                                              int* __restrict__ histE,
                                              int* __restrict__ histT,
                                              int* __restrict__ rankE,
                                              int* __restrict__ rankT) {
    for (int i = blockIdx.x * 256 + TID; i < NT; i += gridDim.x * 256) {
        if (i < NE) rankE[i] = atomicAdd(&histE[nl0[i]], 1);
        rankT[i] = atomicAdd(&histT[tidx[3 * i + 1]], 1);
    }
}

__device__ void scan_one(const int* __restrict__ hist, int* __restrict__ start, int n) {
    __shared__ int wsum[16];
    __shared__ int carryS;
    const int lane = TID & 63;
    const int wv = TID >> 6;
    if (TID == 0) carryS = 0;
    __syncthreads();
    for (int base = 0; base < n; base += 1024) {
        int i = base + TID;
        int v = (i < n) ? hist[i] : 0;
        int acc = v;
        #pragma unroll
        for (int off = 1; off < 64; off <<= 1) {
            int t = __shfl_up(acc, off, 64);
            if (lane >= off) acc += t;
        }
        if (lane == 63) wsum[wv] = acc;
        __syncthreads();
        int woff = 0;
        for (int w = 0; w < wv; ++w) woff += wsum[w];
        int excl = carryS + woff + acc - v;
        if (i < n) start[i] = excl;
        __syncthreads();
        if (TID == 1023) carryS = excl + v;
        __syncthreads();
    }
}

__global__ __launch_bounds__(1024) void k_scan2(const int* __restrict__ hE, int* __restrict__ sE,
                                                const int* __restrict__ hT, int* __restrict__ sT) {
    if (blockIdx.x == 0) scan_one(hE, sE, NN);
    else                 scan_one(hT, sT, NN);
}

// Atomic-free scatter: pos = start[key] + rank[i]; one 8B store per item.
__global__ __launch_bounds__(256) void k_scatter(const int* __restrict__ nl0,
                                                 const int* __restrict__ nl1,
                                                 const float* __restrict__ dist,
                                                 const int* __restrict__ tidx,
                                                 const float* __restrict__ angles,
                                                 const float* __restrict__ rij,
                                                 const float* __restrict__ rik,
                                                 const int* __restrict__ startE,
                                                 const int* __restrict__ startT,
                                                 const int* __restrict__ rankE,
                                                 const int* __restrict__ rankT,
                                                 int2* __restrict__ eS,
                                                 int2* __restrict__ tS) {
    for (int i = blockIdx.x * 256 + TID; i < NT; i += gridDim.x * 256) {
        if (i < NE) {
            int pos = startE[nl0[i]] + rankE[i];
            // fixed-point LUT coordinate: idx = tq>>8, frac = (tq&255)/256
            uint tq = (uint)fmaf(dist[i], 209715.2f, 0.5f);   // d * (4096/5) * 256
            eS[pos] = make_int2((int)tq, nl1[i]);
        }
        int pos = startT[tidx[3 * i + 1]] + rankT[i];
        uint ab = ((uint)__half_as_ushort(__float2half_rn(rik[i])) << 16)
                | (uint)__half_as_ushort(__float2half_rn(rij[i]));
        uint cc = (uint)__half_as_ushort(__float2half_rn(__cosf(angles[i])));
        tS[pos] = make_int2((int)ab, (int)cc);
    }
}

// Fill n0S[pos] = r for pos in [startE[r], startE[r]+histE[r]) — coalesced, wave per r.
__global__ __launch_bounds__(256) void k_fill_n0(const int* __restrict__ startE,
                                                 const int* __restrict__ histE,
                                                 int* __restrict__ n0S) {
    const int lane = TID & 63;
    const int wv = TID >> 6;
    for (int r = blockIdx.x * 4 + wv; r < NN; r += gridDim.x * 4) {
        int s = startE[r], c = histE[r];
        for (int j = lane; j < c; j += 64) n0S[s + j] = r;
    }
}

// Fused: per edge-slot r, usum = sum_t ssp(tbf@W3b1); w3 = usum@W3b2 (in-wave matvec);
// agg[nl0[r]] += h[r]*w3. One wave per r.
__global__ __launch_bounds__(256) void k_trip_node(const int* __restrict__ startT,
                                                   const int* __restrict__ histT,
                                                   const int2* __restrict__ tS,
                                                   const float* __restrict__ W3b1,
                                                   const float* __restrict__ W3b2,
                                                   const ushort* __restrict__ hB,
                                                   const int* __restrict__ nl0,
                                                   float* __restrict__ agg) {
    __shared__ float w2[64 * C];   // 32 KB
    for (int i = TID; i < 64 * C; i += 256) w2[i] = W3b2[i];
    __syncthreads();
    const int lane = TID & 63;
    const int wv = TID >> 6;
    const float w1a = W3b1[lane];
    const float w1b = W3b1[64 + lane];
    const float w1c = W3b1[128 + lane];
    for (int r = blockIdx.x * 4 + wv; r < NN; r += gridDim.x * 4) {
        const int s0 = startT[r];
        const int cnt = histT[r];
        float usum = 0.f;
        for (int base = 0; base < cnt; base += 64) {
            const int n = min(64, cnt - base);
            float ri = 0.f, rk = 0.f, ca = 0.f;
            if (lane < n) {
                int2 p = tS[s0 + base + lane];
                ri = __half2float(__ushort_as_half((ushort)(p.x & 0xFFFF)));
                rk = __half2float(__ushort_as_half((ushort)((uint)p.x >> 16)));
                ca = __half2float(__ushort_as_half((ushort)(p.y & 0xFFFF)));
            }
            for (int i = 0; i < n; ++i) {
                float riB = __shfl(ri, i, 64);
                float rkB = __shfl(rk, i, 64);
                float caB = __shfl(ca, i, 64);
                float x = fmaf(riB, w1a, fmaf(rkB, w1b, caB * w1c));
                usum += ssp(x);
            }
        }
        // w3 = usum-vec @ W3b2; this lane produces cols lane and lane+64
        float o0 = 0.f, o1 = 0.f;
        #pragma unroll 8
        for (int k = 0; k < 64; ++k) {
            float uk = __shfl(usum, k, 64);
            o0 = fmaf(uk, w2[k * C + lane], o0);
            o1 = fmaf(uk, w2[k * C + 64 + lane], o1);
        }
        const int n0 = nl0[r];
        float h0 = bf2f(hB[(size_t)r * C + lane]);
        float h1 = bf2f(hB[(size_t)r * C + 64 + lane]);
        unsafeAtomicAdd(&agg[(size_t)n0 * C + lane], o0 * h0);
        unsafeAtomicAdd(&agg[(size_t)n0 * C + 64 + lane], o1 * h1);
    }
}

// Hot kernel: per sorted edge, out = lerp(lutB, tq) * hB[n1]; run-segmented sum -> agg[n0]
__global__ __launch_bounds__(256) void k_edges_lut(const int2* __restrict__ eS,
                                                   const int* __restrict__ n0S,
                                                   const ushort* __restrict__ hB,
                                                   const ushort* __restrict__ lutB,
                                                   float* __restrict__ agg) {
    __shared__ uint tqsh[256];
    __shared__ int n0sh[256];
    __shared__ int n1sh[256];
    const int c4 = (TID & 31) << 2;
    const int g = TID >> 5;                 // 8 groups x 32 edges
    const int nchunk = NE / 256;
    for (int ch = blockIdx.x; ch < nchunk; ch += gridDim.x) {
        __syncthreads();
        {
            int2 p = eS[ch * 256 + TID];
            tqsh[TID] = (uint)p.x;
            n1sh[TID] = p.y;
            n0sh[TID] = n0S[ch * 256 + TID];
        }
        __syncthreads();
        float4 acc = {0.f, 0.f, 0.f, 0.f};
        int cur = n0sh[g * 32];
        #pragma unroll 4
        for (int j = 0; j < 32; ++j) {
            int e = g * 32 + j;
            uint tq = tqsh[e];
            int idx = min((int)(tq >> 8), LUTN - 2);
            float fr = (float)(tq & 255u) * (1.0f / 256.0f);
            const ushort4 A4 = *(const ushort4*)&lutB[(size_t)idx * C + c4];
            const ushort4 B4 = *(const ushort4*)&lutB[(size_t)(idx + 1) * C + c4];
            const ushort4 hb = *(const ushort4*)&hB[(size_t)n1sh[e] * C + c4];
            float ax = bf2f(A4.x), ay = bf2f(A4.y), az = bf2f(A4.z), aw = bf2f(A4.w);
            float ox = fmaf(fr, bf2f(B4.x) - ax, ax);
            float oy = fmaf(fr, bf2f(B4.y) - ay, ay);
            float oz = fmaf(fr, bf2f(B4.z) - az, az);
            float ow = fmaf(fr, bf2f(B4.w) - aw, aw);
            acc.x = fmaf(ox, bf2f(hb.x), acc.x);
            acc.y = fmaf(oy, bf2f(hb.y), acc.y);
            acc.z = fmaf(oz, bf2f(hb.z), acc.z);
            acc.w = fmaf(ow, bf2f(hb.w), acc.w);
            int nxt = (j < 31) ? n0sh[e + 1] : -1;
            if (nxt != cur) {
                float* dst = &agg[(size_t)cur * C + c4];
                unsafeAtomicAdd(dst + 0, acc.x);
                unsafeAtomicAdd(dst + 1, acc.y);
                unsafeAtomicAdd(dst + 2, acc.z);
                unsafeAtomicAdd(dst + 3, acc.w);
                acc = (float4){0.f, 0.f, 0.f, 0.f};
                cur = nxt;
            }
        }
    }
}

extern "C" void kernel_launch(void* const* d_in, const int* in_sizes, int n_in,
                              void* d_out, int out_size, void* d_ws, size_t ws_size,
                              hipStream_t stream) {
    const float* features = (const float*)d_in[0];
    const float* ndist    = (const float*)d_in[1];
    const int*   nlist    = (const int*)d_in[2];
    const int*   tidx     = (const int*)d_in[3];
    const float* angles   = (const float*)d_in[4];
    const float* rij      = (const float*)d_in[5];
    const float* rik      = (const float*)d_in[6];
    const float* W_pre    = (const float*)d_in[7];
    const float* W2b1     = (const float*)d_in[8];
    const float* W2b2     = (const float*)d_in[9];
    const float* W3b1     = (const float*)d_in[10];
    const float* W3b2     = (const float*)d_in[11];
    const float* W_post   = (const float*)d_in[12];
    float* out = (float*)d_out;

    char* w = (char*)d_ws;
    float* agg   = (float*)w;   w += (size_t)NN * C * 4;    // 10.24 MB
    int* histE   = (int*)w;     w += (size_t)NN * 4;
    int* histT   = (int*)w;     w += (size_t)NN * 4;
    ushort* hB   = (ushort*)w;  w += (size_t)NN * C * 2;    // 5.12 MB
    ushort* lutB = (ushort*)w;  w += (size_t)LUTN * C * 2;  // 1.05 MB
    int2* eS     = (int2*)w;    w += (size_t)NE * 8;        // 5.12 MB
    int2* tS     = (int2*)w;    w += (size_t)NT * 8;        // 8 MB
    int* n0S     = (int*)w;     w += (size_t)NE * 4;        // 2.56 MB
    int* rankE   = (int*)w;     w += (size_t)NE * 4;        // 2.56 MB
    int* rankT   = (int*)w;     w += (size_t)NT * 4;        // 4 MB
    int* startE  = (int*)w;     w += (size_t)NN * 4;
    int* startT  = (int*)w;     w += (size_t)NN * 4;

    const int* nl0 = nlist;
    const int* nl1 = nlist + NE;

    // zero agg + histE + histT (contiguous)
    hipLaunchKernelGGL(k_zero, dim3((NN * C + 2 * NN + 255) / 256), dim3(256), 0, stream,
                       agg, NN * C + 2 * NN);
    hipLaunchKernelGGL(k_gemm16b, dim3((NN + 15) / 16), dim3(256), 0, stream,
                       features, W_pre, hB, NN);
    hipLaunchKernelGGL(k_lut, dim3((LUTN + 7) / 8), dim3(256), 0, stream,
                       W2b1, W2b2, lutB);
    hipLaunchKernelGGL(k_hist, dim3(2048), dim3(256), 0, stream,
                       nl0, tidx, histE, histT, rankE, rankT);
    hipLaunchKernelGGL(k_scan2, dim3(2), dim3(1024), 0, stream,
                       histE, startE, histT, startT);
    hipLaunchKernelGGL(k_scatter, dim3(2048), dim3(256), 0, stream,
                       nl0, nl1, ndist, tidx, angles, rij, rik,
                       startE, startT, rankE, rankT, eS, tS);
    hipLaunchKernelGGL(k_fill_n0, dim3(1250), dim3(256), 0, stream,
                       startE, histE, n0S);
    hipLaunchKernelGGL(k_trip_node, dim3(1250), dim3(256), 0, stream,
                       startT, histT, tS, W3b1, W3b2, hB, nl0, agg);
    hipLaunchKernelGGL(k_edges_lut, dim3(2500), dim3(256), 0, stream,
                       eS, n0S, hB, lutB, agg);
    hipLaunchKernelGGL(k_gemm16f, dim3((NN + 15) / 16), dim3(256), 0, stream,
                       agg, W_post, out, NN);
}

// Round 7
// 330.220 us; speedup vs baseline: 1.3108x; 1.0789x over previous
//
#include <hip/hip_runtime.h>
#include <hip/hip_fp16.h>
#include <math.h>

#define TID threadIdx.x

typedef ushort u16x8 __attribute__((ext_vector_type(8)));

static constexpr int NN = 20000;
static constexpr int NE = 640000;
static constexpr int NT = 1000000;
static constexpr int C = 128;
static constexpr int E = 64;
static constexpr int LUTN = 4104;     // 4097 live rows + zero padding
static constexpr float CUT = 5.0f;
static constexpr float LN2 = 0.69314718055994530942f;

__device__ __forceinline__ float ssp(float x) {
    return fmaxf(x, 0.0f) + __logf(1.0f + __expf(-fabsf(x))) - LN2;
}

// softplus WITHOUT the -LN2 (hoisted by caller)
__device__ __forceinline__ float sp_raw(float x) {
    return fmaxf(x, 0.0f) + __logf(1.0f + __expf(-fabsf(x)));
}

__device__ __forceinline__ ushort f2bf(float x) {
    uint u = __float_as_uint(x);
    return (ushort)((u + 0x7FFFu + ((u >> 16) & 1u)) >> 16);
}

__device__ __forceinline__ float bf2f(ushort u) {
    return __uint_as_float((uint)u << 16);
}

__global__ __launch_bounds__(256) void k_zero(float* __restrict__ p, int n) {
    int i = blockIdx.x * 256 + TID;
    if (i < n) p[i] = 0.0f;
}

// ---- 128x128 GEMM, bf16 weights in LDS, 16 rows per block, no row loop ----
__global__ __launch_bounds__(256) void k_gemm16f(const float* __restrict__ A,
                                                 const float* __restrict__ W,
                                                 float* __restrict__ out, int nrows) {
    __shared__ ushort wB[C * C];       // 32 KB bf16
    __shared__ float aL[16][132];
    for (int i = TID; i < C * C / 4; i += 256) {
        float4 w4 = ((const float4*)W)[i];
        ushort4 u = {f2bf(w4.x), f2bf(w4.y), f2bf(w4.z), f2bf(w4.w)};
        ((ushort4*)wB)[i] = u;
    }
    const int base = blockIdx.x * 16;
    for (int i = TID; i < 512; i += 256) {
        int r = base + (i >> 5);
        float4 v = (r < nrows) ? ((const float4*)A)[(size_t)r * 32 + (i & 31)]
                               : (float4){0.f, 0.f, 0.f, 0.f};
        *(float4*)&aL[i >> 5][(i & 31) << 2] = v;
    }
    __syncthreads();
    const int rg = TID >> 4;
    const int c8 = (TID & 15) << 3;
    float acc[8] = {0.f, 0.f, 0.f, 0.f, 0.f, 0.f, 0.f, 0.f};
    #pragma unroll 8
    for (int k = 0; k < C; ++k) {
        float a = aL[rg][k];
        u16x8 wv = *(const u16x8*)&wB[k * C + c8];
        #pragma unroll
        for (int j = 0; j < 8; ++j) acc[j] = fmaf(a, bf2f(wv[j]), acc[j]);
    }
    int r = base + rg;
    if (r < nrows) {
        float4 o0 = {acc[0], acc[1], acc[2], acc[3]};
        float4 o1 = {acc[4], acc[5], acc[6], acc[7]};
        *(float4*)&out[(size_t)r * C + c8] = o0;
        *(float4*)&out[(size_t)r * C + c8 + 4] = o1;
    }
}

__global__ __launch_bounds__(256) void k_gemm16b(const float* __restrict__ A,
                                                 const float* __restrict__ W,
                                                 ushort* __restrict__ outB, int nrows) {
    __shared__ ushort wB[C * C];
    __shared__ float aL[16][132];
    for (int i = TID; i < C * C / 4; i += 256) {
        float4 w4 = ((const float4*)W)[i];
        ushort4 u = {f2bf(w4.x), f2bf(w4.y), f2bf(w4.z), f2bf(w4.w)};
        ((ushort4*)wB)[i] = u;
    }
    const int base = blockIdx.x * 16;
    for (int i = TID; i < 512; i += 256) {
        int r = base + (i >> 5);
        float4 v = (r < nrows) ? ((const float4*)A)[(size_t)r * 32 + (i & 31)]
                               : (float4){0.f, 0.f, 0.f, 0.f};
        *(float4*)&aL[i >> 5][(i & 31) << 2] = v;
    }
    __syncthreads();
    const int rg = TID >> 4;
    const int c8 = (TID & 15) << 3;
    float acc[8] = {0.f, 0.f, 0.f, 0.f, 0.f, 0.f, 0.f, 0.f};
    #pragma unroll 8
    for (int k = 0; k < C; ++k) {
        float a = aL[rg][k];
        u16x8 wv = *(const u16x8*)&wB[k * C + c8];
        #pragma unroll
        for (int j = 0; j < 8; ++j) acc[j] = fmaf(a, bf2f(wv[j]), acc[j]);
    }
    int r = base + rg;
    if (r < nrows) {
        u16x8 u;
        #pragma unroll
        for (int j = 0; j < 8; ++j) u[j] = f2bf(acc[j]);
        *(u16x8*)&outB[(size_t)r * C + c8] = u;
    }
}

// Build lutB[i][c] = bf16( (ssp(rb(i*delta)@W2b1)@W2b2)[c] ); rows with d>=CUT are 0.
__global__ __launch_bounds__(256) void k_lut(const float* __restrict__ W2b1,
                                             const float* __restrict__ W2b2,
                                             ushort* __restrict__ lutB) {
    __shared__ float w1[E * E];
    __shared__ float w2[E * C];
    __shared__ float rbL[8][E];
    __shared__ float hid[8][E];
    for (int i = TID; i < E * E; i += 256) w1[i] = W2b1[i];
    for (int i = TID; i < E * C; i += 256) w2[i] = W2b2[i];
    const int jj = TID & 63;
    const int esA = TID >> 6;
    const int eg = TID >> 5;
    const int c4 = (TID & 31) << 2;
    const float gamma = 81.92f;
    const float cstep = CUT / 63.0f;
    const float delta = CUT / 4096.0f;
    const int base = blockIdx.x * 8;
    __syncthreads();
    #pragma unroll
    for (int s = 0; s < 2; ++s) {
        int es = esA + 4 * s;
        float d = (float)(base + es) * delta;
        float cv = (d < CUT) ? 0.5f * (1.0f + __cosf((float)M_PI * d / CUT)) : 0.0f;
        float dd = d - (float)jj * cstep;
        rbL[es][jj] = __expf(-gamma * dd * dd) * cv;
    }
    __syncthreads();
    #pragma unroll
    for (int s = 0; s < 2; ++s) {
        int es = esA + 4 * s;
        float a = 0.f;
        #pragma unroll 16
        for (int k = 0; k < E; ++k)
            a = fmaf(rbL[es][k], w1[k * E + jj], a);
        hid[es][jj] = ssp(a);
    }
    __syncthreads();
    float4 o = {0.f, 0.f, 0.f, 0.f};
    #pragma unroll
    for (int j = 0; j < E; ++j) {
        float t = hid[eg][j];
        const float4 w4 = *(const float4*)&w2[j * C + c4];
        o.x = fmaf(t, w4.x, o.x);
        o.y = fmaf(t, w4.y, o.y);
        o.z = fmaf(t, w4.z, o.z);
        o.w = fmaf(t, w4.w, o.w);
    }
    int row = base + eg;
    if (row < LUTN) {
        ushort4 u = {f2bf(o.x), f2bf(o.y), f2bf(o.z), f2bf(o.w)};
        *(ushort4*)&lutB[(size_t)row * C + c4] = u;
    }
}

// Histogram pass ALSO records each item's arrival rank (enables atomic-free scatter).
__global__ __launch_bounds__(256) void k_hist(const int* __restrict__ nl0,
                                              const int* __restrict__ tidx,
                                              int* __restrict__ histE,
                                              int* __restrict__ histT,
                                              int* __restrict__ rankE,
                                              int* __restrict__ rankT) {
    for (int i = blockIdx.x * 256 + TID; i < NT; i += gridDim.x * 256) {
        if (i < NE) rankE[i] = atomicAdd(&histE[nl0[i]], 1);
        rankT[i] = atomicAdd(&histT[tidx[3 * i + 1]], 1);
    }
}

__device__ void scan_one(const int* __restrict__ hist, int* __restrict__ start, int n) {
    __shared__ int wsum[16];
    __shared__ int carryS;
    const int lane = TID & 63;
    const int wv = TID >> 6;
    if (TID == 0) carryS = 0;
    __syncthreads();
    for (int base = 0; base < n; base += 1024) {
        int i = base + TID;
        int v = (i < n) ? hist[i] : 0;
        int acc = v;
        #pragma unroll
        for (int off = 1; off < 64; off <<= 1) {
            int t = __shfl_up(acc, off, 64);
            if (lane >= off) acc += t;
        }
        if (lane == 63) wsum[wv] = acc;
        __syncthreads();
        int woff = 0;
        for (int w = 0; w < wv; ++w) woff += wsum[w];
        int excl = carryS + woff + acc - v;
        if (i < n) start[i] = excl;
        __syncthreads();
        if (TID == 1023) carryS = excl + v;
        __syncthreads();
    }
}

__global__ __launch_bounds__(1024) void k_scan2(const int* __restrict__ hE, int* __restrict__ sE,
                                                const int* __restrict__ hT, int* __restrict__ sT) {
    if (blockIdx.x == 0) scan_one(hE, sE, NN);
    else                 scan_one(hT, sT, NN);
}

// Atomic-free scatter: pos = start[key] + rank[i]; one 8B store per item.
__global__ __launch_bounds__(256) void k_scatter(const int* __restrict__ nl0,
                                                 const int* __restrict__ nl1,
                                                 const float* __restrict__ dist,
                                                 const int* __restrict__ tidx,
                                                 const float* __restrict__ angles,
                                                 const float* __restrict__ rij,
                                                 const float* __restrict__ rik,
                                                 const int* __restrict__ startE,
                                                 const int* __restrict__ startT,
                                                 const int* __restrict__ rankE,
                                                 const int* __restrict__ rankT,
                                                 int2* __restrict__ eS,
                                                 int2* __restrict__ tS) {
    for (int i = blockIdx.x * 256 + TID; i < NT; i += gridDim.x * 256) {
        if (i < NE) {
            int pos = startE[nl0[i]] + rankE[i];
            // fixed-point LUT coordinate: idx = tq>>8, frac = (tq&255)/256
            uint tq = (uint)fmaf(dist[i], 209715.2f, 0.5f);   // d * (4096/5) * 256
            eS[pos] = make_int2((int)tq, nl1[i]);
        }
        int pos = startT[tidx[3 * i + 1]] + rankT[i];
        uint ab = ((uint)__half_as_ushort(__float2half_rn(rik[i])) << 16)
                | (uint)__half_as_ushort(__float2half_rn(rij[i]));
        uint cc = (uint)__half_as_ushort(__float2half_rn(__cosf(angles[i])));
        tS[pos] = make_int2((int)ab, (int)cc);
    }
}

// Fill n0S[pos] = r for pos in [startE[r], startE[r]+histE[r]) — coalesced, wave per r.
__global__ __launch_bounds__(256) void k_fill_n0(const int* __restrict__ startE,
                                                 const int* __restrict__ histE,
                                                 int* __restrict__ n0S) {
    const int lane = TID & 63;
    const int wv = TID >> 6;
    for (int r = blockIdx.x * 4 + wv; r < NN; r += gridDim.x * 4) {
        int s = startE[r], c = histE[r];
        for (int j = lane; j < c; j += 64) n0S[s + j] = r;
    }
}

// Fused triplet kernel, LDS-broadcast version.
// Per node r (one wave): stage 64 triplets into wave-private LDS; inner loop reads
// them with wave-uniform addresses (LDS broadcast, deep prefetchable) — no bpermute.
// usum = sum_t sp_raw(tbf@W3b1) - LN2*cnt; w3 = usum@W3b2; agg[nl0[r]] += h[r]*w3.
__global__ __launch_bounds__(256) void k_trip_node(const int* __restrict__ startT,
                                                   const int* __restrict__ histT,
                                                   const int2* __restrict__ tS,
                                                   const float* __restrict__ W3b1,
                                                   const float* __restrict__ W3b2,
                                                   const ushort* __restrict__ hB,
                                                   const int* __restrict__ nl0,
                                                   float* __restrict__ agg) {
    __shared__ float w2[64 * C];     // 32 KB
    __shared__ uint2 stage[4][64];   // 2 KB, wave-private slots
    for (int i = TID; i < 64 * C; i += 256) w2[i] = W3b2[i];
    __syncthreads();
    const int lane = TID & 63;
    const int wv = TID >> 6;
    const float w1a = W3b1[lane];
    const float w1b = W3b1[64 + lane];
    const float w1c = W3b1[128 + lane];
    for (int r = blockIdx.x * 4 + wv; r < NN; r += gridDim.x * 4) {
        const int s0 = startT[r];
        const int cnt = histT[r];
        float usum = 0.f;
        for (int base = 0; base < cnt; base += 64) {
            const int n = min(64, cnt - base);
            if (lane < n)
                stage[wv][lane] = ((const uint2*)tS)[s0 + base + lane];
            // wave-local LDS RAW: drain lgkm, forbid reordering (no block barrier!)
            asm volatile("s_waitcnt lgkmcnt(0)" ::: "memory");
            #pragma unroll 4
            for (int i = 0; i < n; ++i) {
                uint2 p = stage[wv][i];          // uniform address -> broadcast
                float ri = __half2float(__ushort_as_half((ushort)(p.x & 0xFFFFu)));
                float rk = __half2float(__ushort_as_half((ushort)(p.x >> 16)));
                float ca = __half2float(__ushort_as_half((ushort)(p.y & 0xFFFFu)));
                float x = fmaf(ri, w1a, fmaf(rk, w1b, ca * w1c));
                usum += sp_raw(x);
            }
            asm volatile("s_waitcnt lgkmcnt(0)" ::: "memory");  // reads done before next overwrite
        }
        usum -= LN2 * (float)cnt;
        // w3 = usum-vec @ W3b2; this lane produces cols lane and lane+64
        float o0 = 0.f, o1 = 0.f;
        #pragma unroll 8
        for (int k = 0; k < 64; ++k) {
            float uk = __shfl(usum, k, 64);
            o0 = fmaf(uk, w2[k * C + lane], o0);
            o1 = fmaf(uk, w2[k * C + 64 + lane], o1);
        }
        const int n0 = nl0[r];
        float h0 = bf2f(hB[(size_t)r * C + lane]);
        float h1 = bf2f(hB[(size_t)r * C + 64 + lane]);
        unsafeAtomicAdd(&agg[(size_t)n0 * C + lane], o0 * h0);
        unsafeAtomicAdd(&agg[(size_t)n0 * C + 64 + lane], o1 * h1);
    }
}

// Hot kernel: per sorted edge, out = lerp(lutB, tq) * hB[n1]; run-segmented sum -> agg[n0]
__global__ __launch_bounds__(256) void k_edges_lut(const int2* __restrict__ eS,
                                                   const int* __restrict__ n0S,
                                                   const ushort* __restrict__ hB,
                                                   const ushort* __restrict__ lutB,
                                                   float* __restrict__ agg) {
    __shared__ uint tqsh[256];
    __shared__ int n0sh[256];
    __shared__ int n1sh[256];
    const int c4 = (TID & 31) << 2;
    const int g = TID >> 5;                 // 8 groups x 32 edges
    const int nchunk = NE / 256;
    for (int ch = blockIdx.x; ch < nchunk; ch += gridDim.x) {
        __syncthreads();
        {
            int2 p = eS[ch * 256 + TID];
            tqsh[TID] = (uint)p.x;
            n1sh[TID] = p.y;
            n0sh[TID] = n0S[ch * 256 + TID];
        }
        __syncthreads();
        float4 acc = {0.f, 0.f, 0.f, 0.f};
        int cur = n0sh[g * 32];
        #pragma unroll 4
        for (int j = 0; j < 32; ++j) {
            int e = g * 32 + j;
            uint tq = tqsh[e];
            int idx = min((int)(tq >> 8), LUTN - 2);
            float fr = (float)(tq & 255u) * (1.0f / 256.0f);
            const ushort4 A4 = *(const ushort4*)&lutB[(size_t)idx * C + c4];
            const ushort4 B4 = *(const ushort4*)&lutB[(size_t)(idx + 1) * C + c4];
            const ushort4 hb = *(const ushort4*)&hB[(size_t)n1sh[e] * C + c4];
            float ax = bf2f(A4.x), ay = bf2f(A4.y), az = bf2f(A4.z), aw = bf2f(A4.w);
            float ox = fmaf(fr, bf2f(B4.x) - ax, ax);
            float oy = fmaf(fr, bf2f(B4.y) - ay, ay);
            float oz = fmaf(fr, bf2f(B4.z) - az, az);
            float ow = fmaf(fr, bf2f(B4.w) - aw, aw);
            acc.x = fmaf(ox, bf2f(hb.x), acc.x);
            acc.y = fmaf(oy, bf2f(hb.y), acc.y);
            acc.z = fmaf(oz, bf2f(hb.z), acc.z);
            acc.w = fmaf(ow, bf2f(hb.w), acc.w);
            int nxt = (j < 31) ? n0sh[e + 1] : -1;
            if (nxt != cur) {
                float* dst = &agg[(size_t)cur * C + c4];
                unsafeAtomicAdd(dst + 0, acc.x);
                unsafeAtomicAdd(dst + 1, acc.y);
                unsafeAtomicAdd(dst + 2, acc.z);
                unsafeAtomicAdd(dst + 3, acc.w);
                acc = (float4){0.f, 0.f, 0.f, 0.f};
                cur = nxt;
            }
        }
    }
}

extern "C" void kernel_launch(void* const* d_in, const int* in_sizes, int n_in,
                              void* d_out, int out_size, void* d_ws, size_t ws_size,
                              hipStream_t stream) {
    const float* features = (const float*)d_in[0];
    const float* ndist    = (const float*)d_in[1];
    const int*   nlist    = (const int*)d_in[2];
    const int*   tidx     = (const int*)d_in[3];
    const float* angles   = (const float*)d_in[4];
    const float* rij      = (const float*)d_in[5];
    const float* rik      = (const float*)d_in[6];
    const float* W_pre    = (const float*)d_in[7];
    const float* W2b1     = (const float*)d_in[8];
    const float* W2b2     = (const float*)d_in[9];
    const float* W3b1     = (const float*)d_in[10];
    const float* W3b2     = (const float*)d_in[11];
    const float* W_post   = (const float*)d_in[12];
    float* out = (float*)d_out;

    char* w = (char*)d_ws;
    float* agg   = (float*)w;   w += (size_t)NN * C * 4;    // 10.24 MB
    int* histE   = (int*)w;     w += (size_t)NN * 4;
    int* histT   = (int*)w;     w += (size_t)NN * 4;
    ushort* hB   = (ushort*)w;  w += (size_t)NN * C * 2;    // 5.12 MB
    ushort* lutB = (ushort*)w;  w += (size_t)LUTN * C * 2;  // 1.05 MB
    int2* eS     = (int2*)w;    w += (size_t)NE * 8;        // 5.12 MB
    int2* tS     = (int2*)w;    w += (size_t)NT * 8;        // 8 MB
    int* n0S     = (int*)w;     w += (size_t)NE * 4;        // 2.56 MB
    int* rankE   = (int*)w;     w += (size_t)NE * 4;        // 2.56 MB
    int* rankT   = (int*)w;     w += (size_t)NT * 4;        // 4 MB
    int* startE  = (int*)w;     w += (size_t)NN * 4;
    int* startT  = (int*)w;     w += (size_t)NN * 4;

    const int* nl0 = nlist;
    const int* nl1 = nlist + NE;

    // zero agg + histE + histT (contiguous)
    hipLaunchKernelGGL(k_zero, dim3((NN * C + 2 * NN + 255) / 256), dim3(256), 0, stream,
                       agg, NN * C + 2 * NN);
    hipLaunchKernelGGL(k_gemm16b, dim3((NN + 15) / 16), dim3(256), 0, stream,
                       features, W_pre, hB, NN);
    hipLaunchKernelGGL(k_lut, dim3((LUTN + 7) / 8), dim3(256), 0, stream,
                       W2b1, W2b2, lutB);
    hipLaunchKernelGGL(k_hist, dim3(2048), dim3(256), 0, stream,
                       nl0, tidx, histE, histT, rankE, rankT);
    hipLaunchKernelGGL(k_scan2, dim3(2), dim3(1024), 0, stream,
                       histE, startE, histT, startT);
    hipLaunchKernelGGL(k_scatter, dim3(2048), dim3(256), 0, stream,
                       nl0, nl1, ndist, tidx, angles, rij, rik,
                       startE, startT, rankE, rankT, eS, tS);
    hipLaunchKernelGGL(k_fill_n0, dim3(1250), dim3(256), 0, stream,
                       startE, histE, n0S);
    hipLaunchKernelGGL(k_trip_node, dim3(2500), dim3(256), 0, stream,
                       startT, histT, tS, W3b1, W3b2, hB, nl0, agg);
    hipLaunchKernelGGL(k_edges_lut, dim3(2500), dim3(256), 0, stream,
                       eS, n0S, hB, lutB, agg);
    hipLaunchKernelGGL(k_gemm16f, dim3((NN + 15) / 16), dim3(256), 0, stream,
                       agg, W_post, out, NN);
}